// Round 1
// baseline (10333.575 us; speedup 1.0000x reference)
//
#include <hip/hip_runtime.h>
#include <hip/hip_fp16.h>

#define T_TOK 256
#define NNODE 2049
#define HENC  256
#define DHID  512
#define DIN   800
#define G4    1024
#define DG4   2048
#define RC    92   // packed f16-pair dwords of Whh row held in VGPRs (cols 0..183)
#define TC    36   // packed dwords held in LDS (cols 184..255)

typedef _Float16 f16;
typedef _Float16 f16x2 __attribute__((ext_vector_type(2)));
typedef short    bf16x8 __attribute__((ext_vector_type(8)));
typedef float    f32x4  __attribute__((ext_vector_type(4)));

static __device__ __forceinline__ float sigm(float x){ return 1.0f/(1.0f+__expf(-x)); }
static __device__ __forceinline__ float tanhfast(float x){ return 1.0f - 2.0f/(__expf(2.0f*x)+1.0f); }

static __device__ __forceinline__ unsigned short f2bf(float x){
    unsigned u = __builtin_bit_cast(unsigned, x);
    unsigned r = (u + 0x7fffu + ((u>>16)&1u)) >> 16;
    return (unsigned short)r;
}
static __device__ __forceinline__ unsigned packh2(float a, float b){
    f16 ha = (f16)a, hb = (f16)b;
    unsigned short ua = __builtin_bit_cast(unsigned short, ha);
    unsigned short ub = __builtin_bit_cast(unsigned short, hb);
    return (unsigned)ua | ((unsigned)ub << 16);
}
static __device__ __forceinline__ float fdot2(unsigned wpk, unsigned hpk, float c){
#if __has_builtin(__builtin_amdgcn_fdot2)
    return __builtin_amdgcn_fdot2(__builtin_bit_cast(f16x2, wpk),
                                  __builtin_bit_cast(f16x2, hpk), c, false);
#else
    float d;
    asm volatile("v_dot2_f32_f16 %0, %1, %2, %3" : "=v"(d) : "v"(wpk), "v"(hpk), "v"(c));
    return d;
#endif
}

// ---------------- embedding gather -> bf16 ----------------
__global__ void k_embed(const int* __restrict__ lat,
                        const float* __restrict__ form, const float* __restrict__ lemma,
                        const float* __restrict__ tag,  const float* __restrict__ feats,
                        unsigned short* __restrict__ embB){
    int n = blockIdx.x;
    const int* L = lat + n*11;
    int i0 = L[0], i1 = L[1], i2 = L[2];
    for (int c = threadIdx.x; c < DIN; c += blockDim.x){
        float v;
        if (c < 300)      v = form[i0*300 + c];
        else if (c < 600) v = lemma[i1*300 + (c-300)];
        else if (c < 700) v = tag[i2*100 + (c-600)];
        else {
            float s = 0.f;
            #pragma unroll
            for (int j=0;j<6;++j) s += feats[L[3+j]*100 + (c-700)];
            v = s * (1.0f/6.0f);
        }
        embB[n*DIN + c] = f2bf(v);
    }
}

__global__ void k_f32_to_bf16(const float* __restrict__ src, unsigned short* __restrict__ dst, int n){
    int i = blockIdx.x*blockDim.x + threadIdx.x;
    if (i < n) dst[i] = f2bf(src[i]);
}

// pack Whh (both dirs) into f16-pair dword layouts: wregT[d][k][row], wtail[d][w][row]
__global__ void k_pack_whh(const float* __restrict__ wf, const float* __restrict__ wb,
                           unsigned* __restrict__ wregT, unsigned* __restrict__ wtail){
    int id = blockIdx.x*blockDim.x + threadIdx.x;
    if (id >= 2048) return;
    int d = id >> 10, r = id & 1023;
    const float* W = (d ? wb : wf) + r*256;
    for (int k=0;k<RC;++k) wregT[(d*RC + k)*1024 + r] = packh2(W[2*k], W[2*k+1]);
    for (int w=0;w<TC;++w) wtail[(d*TC + w)*1024 + r] = packh2(W[184+2*w], W[185+2*w]);
}

// ---------------- bf16 MFMA GEMM: C[M][Nc] = A[M][K] * B[Nc][K]^T (+bias) ----------------
__global__ __launch_bounds__(256) void k_gemm_bf16(const unsigned short* __restrict__ A,
                                                   const unsigned short* __restrict__ B,
                                                   float* __restrict__ C,
                                                   const float* __restrict__ bias,
                                                   int M, int Nc, int K){
    __shared__ unsigned short As[64][40];
    __shared__ unsigned short Bs[64][40];
    int m0 = blockIdx.x*64, n0 = blockIdx.y*64;
    int t = threadIdx.x, w = t>>6, lane = t&63;
    f32x4 acc[4];
    #pragma unroll
    for (int i=0;i<4;++i) acc[i] = (f32x4){0.f,0.f,0.f,0.f};
    int rowl = t>>2, kb0 = (t&3)*8;
    for (int k0=0; k0<K; k0+=32){
        uint4 av;
        int ar = m0 + rowl;
        if (ar < M) av = *(const uint4*)(A + ar*K + k0 + kb0);
        else { av.x=av.y=av.z=av.w=0u; }
        *(uint4*)&As[rowl][kb0] = av;
        *(uint4*)&Bs[rowl][kb0] = *(const uint4*)(B + (n0+rowl)*K + k0 + kb0);
        __syncthreads();
        int arow = w*16 + (lane&15), kk = (lane>>4)*8;
        bf16x8 af = *(const bf16x8*)&As[arow][kk];
        #pragma unroll
        for (int nt=0;nt<4;++nt){
            bf16x8 bf = *(const bf16x8*)&Bs[nt*16 + (lane&15)][kk];
            acc[nt] = __builtin_amdgcn_mfma_f32_16x16x32_bf16(af, bf, acc[nt], 0,0,0);
        }
        __syncthreads();
    }
    #pragma unroll
    for (int nt=0;nt<4;++nt){
        int col = n0 + nt*16 + (lane&15);
        float bb = bias ? bias[col] : 0.0f;
        #pragma unroll
        for (int r=0;r<4;++r){
            int row = m0 + w*16 + (lane>>4)*4 + r;
            if (row < M) C[row*Nc + col] = acc[nt][r] + bb;
        }
    }
}

// ---------------- sequential bi-LSTM scan, one workgroup per direction ----------------
__global__ __launch_bounds__(1024) void k_lstm_scan(const unsigned* __restrict__ wregT,
                                                    const unsigned* __restrict__ wtail,
                                                    const float* __restrict__ XgF,
                                                    const float* __restrict__ XgB,
                                                    float* __restrict__ encoded,
                                                    float* __restrict__ h0,
                                                    float* __restrict__ c0){
    extern __shared__ char smem[];
    unsigned* sTail = (unsigned*)smem;                       // TC*1024 dwords
    unsigned* sHpk  = (unsigned*)(smem + TC*1024*4);         // 128 dwords (256 h as f16)
    float*    sG    = (float*)(smem + TC*1024*4 + 512);      // 1024 f32
    int dir = blockIdx.x;
    int t = threadIdx.x;
    const float* Xg = dir ? XgB : XgF;

    unsigned w[RC];
    #pragma unroll
    for (int k=0;k<RC;++k) w[k] = wregT[(dir*RC + k)*1024 + t];
    #pragma unroll
    for (int k=0;k<TC;++k) sTail[k*1024 + t] = wtail[(dir*TC + k)*1024 + t];
    if (t < 128) sHpk[t] = 0u;
    float c_reg = 0.0f;
    __syncthreads();

    const uint4* sH4 = (const uint4*)sHpk;
    for (int s=0; s<NNODE; ++s){
        int node = dir ? (NNODE-1-s) : s;
        float xg = Xg[node*G4 + t];
        float a0=0.f,a1=0.f,a2=0.f,a3=0.f;
        #pragma unroll
        for (int kb=0;kb<23;++kb){
            uint4 hv = sH4[kb];
            a0 = fdot2(w[4*kb+0], hv.x, a0);
            a1 = fdot2(w[4*kb+1], hv.y, a1);
            a2 = fdot2(w[4*kb+2], hv.z, a2);
            a3 = fdot2(w[4*kb+3], hv.w, a3);
        }
        #pragma unroll
        for (int wb=0; wb<9; ++wb){
            uint4 hv = sH4[23+wb];
            a0 = fdot2(sTail[(4*wb+0)*1024 + t], hv.x, a0);
            a1 = fdot2(sTail[(4*wb+1)*1024 + t], hv.y, a1);
            a2 = fdot2(sTail[(4*wb+2)*1024 + t], hv.z, a2);
            a3 = fdot2(sTail[(4*wb+3)*1024 + t], hv.w, a3);
        }
        float g = ((a0+a1)+(a2+a3)) + xg;
        sG[t] = g;
        __syncthreads();
        if (t < 256){
            float gi = sG[t], gf = sG[256+t], gg = sG[512+t], go = sG[768+t];
            float c = sigm(gf)*c_reg + sigm(gi)*tanhfast(gg);
            c_reg = c;
            float h = sigm(go)*tanhfast(c);
            ((f16*)sHpk)[t] = (f16)h;
            encoded[node*DHID + dir*HENC + t] = h;
            if (s == NNODE-1){ h0[dir*HENC + t] = h; c0[dir*HENC + t] = c; }
        }
        __syncthreads();
    }
}

// Kd = dec_whh @ h0 + dec_b
__global__ void k_dec_const(const float* __restrict__ dec_whh, const float* __restrict__ dec_b,
                            const float* __restrict__ h0, float* __restrict__ Kd){
    __shared__ float sh[512];
    int t = threadIdx.x;
    int r = blockIdx.x*256 + t;
    sh[t] = h0[t]; sh[256+t] = h0[256+t];
    __syncthreads();
    float a = 0.f;
    const float* Wr = dec_whh + r*512;
    for (int k=0;k<512;++k) a += Wr[k]*sh[k];
    Kd[r] = a + dec_b[r];
}

// decoder h for every possible ptr node
__global__ void k_hall(const float* __restrict__ G, const float* __restrict__ Kd,
                       const float* __restrict__ c0, float* __restrict__ Hall){
    int n = blockIdx.x, u = threadIdx.x;
    const float* g = G + n*DG4;
    float gi = g[u]        + Kd[u];
    float gf = g[512+u]    + Kd[512+u];
    float gg = g[1024+u]   + Kd[1024+u];
    float go = g[1536+u]   + Kd[1536+u];
    float c  = sigm(gf)*c0[u] + sigm(gi)*tanhfast(gg);
    Hall[n*DHID + u] = sigm(go)*tanhfast(c);
}

// S[i][p][c] = encoded[cand(i,c)] . Hall[prev(i,p)]
__global__ __launch_bounds__(256) void k_scores(const float* __restrict__ encoded,
                                                const float* __restrict__ Hall,
                                                float* __restrict__ S){
    __shared__ float sE[8][512];
    __shared__ float sHp[8][512];
    int i = blockIdx.x, t = threadIdx.x;
    for (int idx = t; idx < 8*512; idx += 256){
        int r = idx >> 9, c = idx & 511;
        int cand = 1 + i*8 + r;
        sE[r][c] = encoded[cand*DHID + c];
        int prev = (i==0) ? 0 : (1 + (i-1)*8 + r);
        sHp[r][c] = Hall[prev*DHID + c];
    }
    __syncthreads();
    int w = t>>6, lane = t&63;
    for (int q=0;q<16;++q){
        int pi = w*16 + q, p = pi>>3, c = pi&7;
        float v = 0.f;
        #pragma unroll
        for (int j=0;j<8;++j) v += sE[c][lane*8+j]*sHp[p][lane*8+j];
        #pragma unroll
        for (int off=32; off; off>>=1) v += __shfl_xor(v, off);
        if (lane==0) S[i*64 + p*8 + c] = v;
    }
}

// sequential pointer chain + loss
__global__ __launch_bounds__(256) void k_decode(const float* __restrict__ S, float* __restrict__ out){
    __shared__ float nll[2048];
    __shared__ int   cst[2048];
    __shared__ int   path[256];
    __shared__ float wsum[4];
    int t = threadIdx.x;
    for (int p=0;p<8;++p){
        const float* s = S + t*64 + p*8;
        float m = s[0]; int am = 0;
        #pragma unroll
        for (int c=1;c<8;++c){ float v = s[c]; if (v > m){ m = v; am = c; } }
        float e = 0.f;
        #pragma unroll
        for (int c=0;c<8;++c) e += __expf(s[c]-m);
        float lse = m + __logf(e);
        nll[t*8+p] = lse - s[0];
        cst[t*8+p] = am;
    }
    __syncthreads();
    if (t == 0){
        int p = 0;
        for (int i=0;i<256;++i){
            int idx = i*8 + p;
            path[i] = idx;
            int c = cst[idx];
            out[i+1] = (float)(1 + i*8 + c);
            p = c;
        }
        out[0] = 0.0f;
    }
    __syncthreads();
    float v = nll[path[t]];
    #pragma unroll
    for (int off=32; off; off>>=1) v += __shfl_xor(v, off);
    if ((t&63)==0) wsum[t>>6] = v;
    __syncthreads();
    if (t==0) out[257] = (wsum[0]+wsum[1]+wsum[2]+wsum[3]) * (1.0f/256.0f);
}

extern "C" void kernel_launch(void* const* d_in, const int* in_sizes, int n_in,
                              void* d_out, int out_size, void* d_ws, size_t ws_size,
                              hipStream_t stream){
    (void)in_sizes; (void)n_in; (void)out_size; (void)ws_size;
    const int*   lattice  = (const int*)  d_in[0];
    const float* form     = (const float*)d_in[2];
    const float* lemma    = (const float*)d_in[3];
    const float* tag      = (const float*)d_in[4];
    const float* feats    = (const float*)d_in[5];
    const float* wih_f    = (const float*)d_in[6];
    const float* whh_f    = (const float*)d_in[7];
    const float* b_f      = (const float*)d_in[8];
    const float* wih_b    = (const float*)d_in[9];
    const float* whh_b    = (const float*)d_in[10];
    const float* b_b      = (const float*)d_in[11];
    const float* dwih     = (const float*)d_in[12];
    const float* dwhh     = (const float*)d_in[13];
    const float* db       = (const float*)d_in[14];
    float* out = (float*)d_out;

    char* ws = (char*)d_ws;
    size_t o = 0;
    auto alloc = [&](size_t bytes)->char*{ char* p = ws + o; o = (o + bytes + 255) & ~(size_t)255; return p; };
    unsigned short* embB   = (unsigned short*)alloc((size_t)NNODE*DIN*2);
    unsigned short* wihfB  = (unsigned short*)alloc((size_t)G4*DIN*2);
    unsigned short* wihbB  = (unsigned short*)alloc((size_t)G4*DIN*2);
    unsigned short* dwihB  = (unsigned short*)alloc((size_t)DG4*DIN*2);
    unsigned*       wregT  = (unsigned*)alloc((size_t)2*RC*1024*4);
    unsigned*       wtail  = (unsigned*)alloc((size_t)2*TC*1024*4);
    float*          XgF    = (float*)alloc((size_t)NNODE*G4*4);
    float*          XgB    = (float*)alloc((size_t)NNODE*G4*4);
    float*          Graw   = (float*)alloc((size_t)NNODE*DG4*4);
    float*          enc    = (float*)alloc((size_t)NNODE*DHID*4);
    float*          h0     = (float*)alloc(512*4);
    float*          c0     = (float*)alloc(512*4);
    float*          Kd     = (float*)alloc(2048*4);
    float*          Hall   = (float*)alloc((size_t)NNODE*DHID*4);
    float*          Sbuf   = (float*)alloc((size_t)256*64*4);

    hipFuncSetAttribute(reinterpret_cast<const void*>(k_lstm_scan),
                        hipFuncAttributeMaxDynamicSharedMemorySize, TC*1024*4 + 512 + 4096);

    k_f32_to_bf16<<<(G4*DIN+255)/256, 256, 0, stream>>>(wih_f, wihfB, G4*DIN);
    k_f32_to_bf16<<<(G4*DIN+255)/256, 256, 0, stream>>>(wih_b, wihbB, G4*DIN);
    k_f32_to_bf16<<<(DG4*DIN+255)/256, 256, 0, stream>>>(dwih, dwihB, DG4*DIN);
    k_pack_whh<<<8, 256, 0, stream>>>(whh_f, whh_b, wregT, wtail);
    k_embed<<<NNODE, 256, 0, stream>>>(lattice, form, lemma, tag, feats, embB);

    dim3 gE((NNODE+63)/64, G4/64);
    k_gemm_bf16<<<gE, 256, 0, stream>>>(embB, wihfB, XgF, b_f, NNODE, G4, DIN);
    k_gemm_bf16<<<gE, 256, 0, stream>>>(embB, wihbB, XgB, b_b, NNODE, G4, DIN);
    dim3 gD((NNODE+63)/64, DG4/64);
    k_gemm_bf16<<<gD, 256, 0, stream>>>(embB, dwihB, Graw, nullptr, NNODE, DG4, DIN);

    k_lstm_scan<<<2, 1024, TC*1024*4 + 512 + 4096, stream>>>(wregT, wtail, XgF, XgB, enc, h0, c0);

    k_dec_const<<<8, 256, 0, stream>>>(dwhh, db, h0, Kd);
    k_hall<<<NNODE, 512, 0, stream>>>(Graw, Kd, c0, Hall);
    k_scores<<<256, 256, 0, stream>>>(enc, Hall, Sbuf);
    k_decode<<<1, 256, 0, stream>>>(Sbuf, out);
}

// Round 2
// 4579.579 us; speedup vs baseline: 2.2564x; 2.2564x over previous
//
#include <hip/hip_runtime.h>
#include <hip/hip_fp16.h>

#define T_TOK 256
#define NNODE 2049
#define HENC  256
#define DHID  512
#define DIN   800
#define G4    1024
#define DG4   2048

typedef _Float16 f16;
typedef _Float16 f16x2 __attribute__((ext_vector_type(2)));
typedef short    bf16x8 __attribute__((ext_vector_type(8)));
typedef float    f32x4  __attribute__((ext_vector_type(4)));

static __device__ __forceinline__ float sigm(float x){ return 1.0f/(1.0f+__expf(-x)); }
static __device__ __forceinline__ float tanhfast(float x){ return 1.0f - 2.0f/(__expf(2.0f*x)+1.0f); }

static __device__ __forceinline__ unsigned short f2bf(float x){
    unsigned u = __builtin_bit_cast(unsigned, x);
    unsigned r = (u + 0x7fffu + ((u>>16)&1u)) >> 16;
    return (unsigned short)r;
}
static __device__ __forceinline__ unsigned packh2(float a, float b){
    f16 ha = (f16)a, hb = (f16)b;
    unsigned short ua = __builtin_bit_cast(unsigned short, ha);
    unsigned short ub = __builtin_bit_cast(unsigned short, hb);
    return (unsigned)ua | ((unsigned)ub << 16);
}
static __device__ __forceinline__ float fdot2(unsigned wpk, unsigned hpk, float c){
#if __has_builtin(__builtin_amdgcn_fdot2)
    return __builtin_amdgcn_fdot2(__builtin_bit_cast(f16x2, wpk),
                                  __builtin_bit_cast(f16x2, hpk), c, false);
#else
    float d;
    asm volatile("v_dot2_f32_f16 %0, %1, %2, %3" : "=v"(d) : "v"(wpk), "v"(hpk), "v"(c));
    return d;
#endif
}

// ---------------- embedding gather -> bf16 ----------------
__global__ void k_embed(const int* __restrict__ lat,
                        const float* __restrict__ form, const float* __restrict__ lemma,
                        const float* __restrict__ tag,  const float* __restrict__ feats,
                        unsigned short* __restrict__ embB){
    int n = blockIdx.x;
    const int* L = lat + n*11;
    int i0 = L[0], i1 = L[1], i2 = L[2];
    for (int c = threadIdx.x; c < DIN; c += blockDim.x){
        float v;
        if (c < 300)      v = form[i0*300 + c];
        else if (c < 600) v = lemma[i1*300 + (c-300)];
        else if (c < 700) v = tag[i2*100 + (c-600)];
        else {
            float s = 0.f;
            #pragma unroll
            for (int j=0;j<6;++j) s += feats[L[3+j]*100 + (c-700)];
            v = s * (1.0f/6.0f);
        }
        embB[n*DIN + c] = f2bf(v);
    }
}

__global__ void k_f32_to_bf16(const float* __restrict__ src, unsigned short* __restrict__ dst, int n){
    int i = blockIdx.x*blockDim.x + threadIdx.x;
    if (i < n) dst[i] = f2bf(src[i]);
}

// pack Whh for scan v2: thread t owns rows t and t+512.
// wreg[d][k][t] dwords: k=0..95 -> row t cols 0..191 ; k=96..191 -> row t+512 cols 0..191
// wtail[d][w][t] uint4 : w=0..7 -> row t cols 192..255 ; w=8..15 -> row t+512 cols 192..255
__global__ void k_pack_whh(const float* __restrict__ wf, const float* __restrict__ wb,
                           unsigned* __restrict__ wreg, uint4* __restrict__ wtail){
    int id = blockIdx.x*blockDim.x + threadIdx.x;
    if (id >= 1024) return;
    int d = id >> 9, t = id & 511;
    const float* W  = d ? wb : wf;
    const float* R0 = W + (size_t)t*256;
    const float* R1 = W + (size_t)(t+512)*256;
    for (int k=0;k<96;++k){
        wreg[(d*192 + k)*512 + t]      = packh2(R0[2*k], R0[2*k+1]);
        wreg[(d*192 + 96 + k)*512 + t] = packh2(R1[2*k], R1[2*k+1]);
    }
    for (int w=0;w<8;++w){
        uint4 v;
        v.x = packh2(R0[192+8*w+0], R0[192+8*w+1]);
        v.y = packh2(R0[192+8*w+2], R0[192+8*w+3]);
        v.z = packh2(R0[192+8*w+4], R0[192+8*w+5]);
        v.w = packh2(R0[192+8*w+6], R0[192+8*w+7]);
        wtail[(d*16 + w)*512 + t] = v;
        v.x = packh2(R1[192+8*w+0], R1[192+8*w+1]);
        v.y = packh2(R1[192+8*w+2], R1[192+8*w+3]);
        v.z = packh2(R1[192+8*w+4], R1[192+8*w+5]);
        v.w = packh2(R1[192+8*w+6], R1[192+8*w+7]);
        wtail[(d*16 + 8 + w)*512 + t] = v;
    }
}

// ---------------- bf16 MFMA GEMM: C[M][Nc] = A[M][K] * B[Nc][K]^T (+bias) ----------------
__global__ __launch_bounds__(256) void k_gemm_bf16(const unsigned short* __restrict__ A,
                                                   const unsigned short* __restrict__ B,
                                                   float* __restrict__ C,
                                                   const float* __restrict__ bias,
                                                   int M, int Nc, int K){
    __shared__ unsigned short As[64][40];
    __shared__ unsigned short Bs[64][40];
    int m0 = blockIdx.x*64, n0 = blockIdx.y*64;
    int t = threadIdx.x, w = t>>6, lane = t&63;
    f32x4 acc[4];
    #pragma unroll
    for (int i=0;i<4;++i) acc[i] = (f32x4){0.f,0.f,0.f,0.f};
    int rowl = t>>2, kb0 = (t&3)*8;
    for (int k0=0; k0<K; k0+=32){
        uint4 av;
        int ar = m0 + rowl;
        if (ar < M) av = *(const uint4*)(A + (size_t)ar*K + k0 + kb0);
        else { av.x=av.y=av.z=av.w=0u; }
        *(uint4*)&As[rowl][kb0] = av;
        *(uint4*)&Bs[rowl][kb0] = *(const uint4*)(B + (size_t)(n0+rowl)*K + k0 + kb0);
        __syncthreads();
        int arow = w*16 + (lane&15), kk = (lane>>4)*8;
        bf16x8 af = *(const bf16x8*)&As[arow][kk];
        #pragma unroll
        for (int nt=0;nt<4;++nt){
            bf16x8 bf = *(const bf16x8*)&Bs[nt*16 + (lane&15)][kk];
            acc[nt] = __builtin_amdgcn_mfma_f32_16x16x32_bf16(af, bf, acc[nt], 0,0,0);
        }
        __syncthreads();
    }
    #pragma unroll
    for (int nt=0;nt<4;++nt){
        int col = n0 + nt*16 + (lane&15);
        float bb = bias ? bias[col] : 0.0f;
        #pragma unroll
        for (int r=0;r<4;++r){
            int row = m0 + w*16 + (lane>>4)*4 + r;
            if (row < M) C[(size_t)row*Nc + col] = acc[nt][r] + bb;
        }
    }
}

// ---------------- sequential bi-LSTM scan v2: 512 threads, 2 rows/thread ----------------
__global__ __launch_bounds__(512, 2) void k_lstm_scan(const unsigned* __restrict__ wreg,
                                                      const uint4* __restrict__ wtail,
                                                      const float* __restrict__ XgF,
                                                      const float* __restrict__ XgB,
                                                      float* __restrict__ encoded,
                                                      float* __restrict__ h0,
                                                      float* __restrict__ c0){
    extern __shared__ char smem[];
    uint4*    sT4  = (uint4*)smem;                    // 16*512 uint4 = 131072 B
    unsigned* sHpk = (unsigned*)(smem + 131072);      // 128 dwords (256 h as f16)
    float*    sX   = (float*)(smem + 131072 + 512);   // 256 f32
    int dir = blockIdx.x;
    int t = threadIdx.x;
    const float* Xg = dir ? XgB : XgF;

    unsigned w[192];
    #pragma unroll
    for (int k=0;k<192;++k) w[k] = wreg[(dir*192 + k)*512 + t];
    #pragma unroll
    for (int k=0;k<16;++k) sT4[k*512 + t] = wtail[(dir*16 + k)*512 + t];
    if (t < 128) sHpk[t] = 0u;
    float c_reg = 0.0f;
    __syncthreads();

    const uint4* sH4 = (const uint4*)sHpk;
    int node  = dir ? (NNODE-1) : 0;
    int stepd = dir ? -1 : 1;
    float xg0 = Xg[(size_t)node*G4 + t];
    float xg1 = Xg[(size_t)node*G4 + 512 + t];

    for (int s=0; s<NNODE; ++s){
        float xn0 = 0.f, xn1 = 0.f;
        if (s+1 < NNODE){
            int nn = node + stepd;
            xn0 = Xg[(size_t)nn*G4 + t];
            xn1 = Xg[(size_t)nn*G4 + 512 + t];
        }
        float a0=0.f,a1=0.f,a2=0.f,a3=0.f;
        #pragma unroll
        for (int kb=0;kb<24;++kb){
            uint4 hv = sH4[kb];
            a0 = fdot2(w[4*kb+0],    hv.x, a0);
            a1 = fdot2(w[4*kb+1],    hv.y, a1);
            a0 = fdot2(w[4*kb+2],    hv.z, a0);
            a1 = fdot2(w[4*kb+3],    hv.w, a1);
            a2 = fdot2(w[96+4*kb+0], hv.x, a2);
            a3 = fdot2(w[96+4*kb+1], hv.y, a3);
            a2 = fdot2(w[96+4*kb+2], hv.z, a2);
            a3 = fdot2(w[96+4*kb+3], hv.w, a3);
        }
        #pragma unroll
        for (int kb=24;kb<32;++kb){
            uint4 hv = sH4[kb];
            uint4 w0 = sT4[(kb-24)*512 + t];
            uint4 w1 = sT4[(8+kb-24)*512 + t];
            a0 = fdot2(w0.x, hv.x, a0);
            a1 = fdot2(w0.y, hv.y, a1);
            a0 = fdot2(w0.z, hv.z, a0);
            a1 = fdot2(w0.w, hv.w, a1);
            a2 = fdot2(w1.x, hv.x, a2);
            a3 = fdot2(w1.y, hv.y, a3);
            a2 = fdot2(w1.z, hv.z, a2);
            a3 = fdot2(w1.w, hv.w, a3);
        }
        float g0 = (a0+a1) + xg0;
        float g1 = (a2+a3) + xg1;
        if (t < 256) sX[t] = sigm(g0) * tanhfast(g1);
        __syncthreads();
        if (t >= 256){
            int u = t - 256;
            float c = sigm(g0)*c_reg + sX[u];
            c_reg = c;
            float h = sigm(g1)*tanhfast(c);
            ((f16*)sHpk)[u] = (f16)h;
            encoded[(size_t)node*DHID + dir*HENC + u] = h;
            if (s == NNODE-1){ h0[dir*HENC + u] = h; c0[dir*HENC + u] = c; }
        }
        __syncthreads();
        node += stepd; xg0 = xn0; xg1 = xn1;
    }
}

// Kd = dec_whh @ h0 + dec_b
__global__ void k_dec_const(const float* __restrict__ dec_whh, const float* __restrict__ dec_b,
                            const float* __restrict__ h0, float* __restrict__ Kd){
    __shared__ float sh[512];
    int t = threadIdx.x;
    int r = blockIdx.x*256 + t;
    sh[t] = h0[t]; sh[256+t] = h0[256+t];
    __syncthreads();
    float a = 0.f;
    const float* Wr = dec_whh + (size_t)r*512;
    for (int k=0;k<512;++k) a += Wr[k]*sh[k];
    Kd[r] = a + dec_b[r];
}

// decoder h for every possible ptr node
__global__ void k_hall(const float* __restrict__ G, const float* __restrict__ Kd,
                       const float* __restrict__ c0, float* __restrict__ Hall){
    int n = blockIdx.x, u = threadIdx.x;
    const float* g = G + (size_t)n*DG4;
    float gi = g[u]        + Kd[u];
    float gf = g[512+u]    + Kd[512+u];
    float gg = g[1024+u]   + Kd[1024+u];
    float go = g[1536+u]   + Kd[1536+u];
    float c  = sigm(gf)*c0[u] + sigm(gi)*tanhfast(gg);
    Hall[(size_t)n*DHID + u] = sigm(go)*tanhfast(c);
}

// S[i][p][c] = encoded[cand(i,c)] . Hall[prev(i,p)]
__global__ __launch_bounds__(256) void k_scores(const float* __restrict__ encoded,
                                                const float* __restrict__ Hall,
                                                float* __restrict__ S){
    __shared__ float sE[8][512];
    __shared__ float sHp[8][512];
    int i = blockIdx.x, t = threadIdx.x;
    for (int idx = t; idx < 8*512; idx += 256){
        int r = idx >> 9, c = idx & 511;
        int cand = 1 + i*8 + r;
        sE[r][c] = encoded[(size_t)cand*DHID + c];
        int prev = (i==0) ? 0 : (1 + (i-1)*8 + r);
        sHp[r][c] = Hall[(size_t)prev*DHID + c];
    }
    __syncthreads();
    int w = t>>6, lane = t&63;
    for (int q=0;q<16;++q){
        int pi = w*16 + q, p = pi>>3, c = pi&7;
        float v = 0.f;
        #pragma unroll
        for (int j=0;j<8;++j) v += sE[c][lane*8+j]*sHp[p][lane*8+j];
        #pragma unroll
        for (int off=32; off; off>>=1) v += __shfl_xor(v, off);
        if (lane==0) S[i*64 + p*8 + c] = v;
    }
}

// sequential pointer chain + loss
__global__ __launch_bounds__(256) void k_decode(const float* __restrict__ S, float* __restrict__ out){
    __shared__ float nll[2048];
    __shared__ int   cst[2048];
    __shared__ int   path[256];
    __shared__ float wsum[4];
    int t = threadIdx.x;
    for (int p=0;p<8;++p){
        const float* s = S + t*64 + p*8;
        float m = s[0]; int am = 0;
        #pragma unroll
        for (int c=1;c<8;++c){ float v = s[c]; if (v > m){ m = v; am = c; } }
        float e = 0.f;
        #pragma unroll
        for (int c=0;c<8;++c) e += __expf(s[c]-m);
        float lse = m + __logf(e);
        nll[t*8+p] = lse - s[0];
        cst[t*8+p] = am;
    }
    __syncthreads();
    if (t == 0){
        int p = 0;
        for (int i=0;i<256;++i){
            int idx = i*8 + p;
            path[i] = idx;
            int c = cst[idx];
            out[i+1] = (float)(1 + i*8 + c);
            p = c;
        }
        out[0] = 0.0f;
    }
    __syncthreads();
    float v = nll[path[t]];
    #pragma unroll
    for (int off=32; off; off>>=1) v += __shfl_xor(v, off);
    if ((t&63)==0) wsum[t>>6] = v;
    __syncthreads();
    if (t==0) out[257] = (wsum[0]+wsum[1]+wsum[2]+wsum[3]) * (1.0f/256.0f);
}

extern "C" void kernel_launch(void* const* d_in, const int* in_sizes, int n_in,
                              void* d_out, int out_size, void* d_ws, size_t ws_size,
                              hipStream_t stream){
    (void)in_sizes; (void)n_in; (void)out_size; (void)ws_size;
    const int*   lattice  = (const int*)  d_in[0];
    const float* form     = (const float*)d_in[2];
    const float* lemma    = (const float*)d_in[3];
    const float* tag      = (const float*)d_in[4];
    const float* feats    = (const float*)d_in[5];
    const float* wih_f    = (const float*)d_in[6];
    const float* whh_f    = (const float*)d_in[7];
    const float* b_f      = (const float*)d_in[8];
    const float* wih_b    = (const float*)d_in[9];
    const float* whh_b    = (const float*)d_in[10];
    const float* b_b      = (const float*)d_in[11];
    const float* dwih     = (const float*)d_in[12];
    const float* dwhh     = (const float*)d_in[13];
    const float* db       = (const float*)d_in[14];
    float* out = (float*)d_out;

    char* ws = (char*)d_ws;
    size_t o = 0;
    auto alloc = [&](size_t bytes)->char*{ char* p = ws + o; o = (o + bytes + 255) & ~(size_t)255; return p; };
    unsigned short* embB   = (unsigned short*)alloc((size_t)NNODE*DIN*2);
    unsigned short* wihfB  = (unsigned short*)alloc((size_t)G4*DIN*2);
    unsigned short* wihbB  = (unsigned short*)alloc((size_t)G4*DIN*2);
    unsigned short* dwihB  = (unsigned short*)alloc((size_t)DG4*DIN*2);
    unsigned*       wreg   = (unsigned*)alloc((size_t)2*192*512*4);
    uint4*          wtail  = (uint4*)alloc((size_t)2*16*512*16);
    float*          XgF    = (float*)alloc((size_t)NNODE*G4*4);
    float*          XgB    = (float*)alloc((size_t)NNODE*G4*4);
    float*          Graw   = (float*)alloc((size_t)NNODE*DG4*4);
    float*          enc    = (float*)alloc((size_t)NNODE*DHID*4);
    float*          h0     = (float*)alloc(512*4);
    float*          c0     = (float*)alloc(512*4);
    float*          Kd     = (float*)alloc(2048*4);
    float*          Hall   = (float*)alloc((size_t)NNODE*DHID*4);
    float*          Sbuf   = (float*)alloc((size_t)256*64*4);

    const int scan_lds = 131072 + 512 + 1024;
    hipFuncSetAttribute(reinterpret_cast<const void*>(k_lstm_scan),
                        hipFuncAttributeMaxDynamicSharedMemorySize, scan_lds);

    k_f32_to_bf16<<<(G4*DIN+255)/256, 256, 0, stream>>>(wih_f, wihfB, G4*DIN);
    k_f32_to_bf16<<<(G4*DIN+255)/256, 256, 0, stream>>>(wih_b, wihbB, G4*DIN);
    k_f32_to_bf16<<<(DG4*DIN+255)/256, 256, 0, stream>>>(dwih, dwihB, DG4*DIN);
    k_pack_whh<<<4, 256, 0, stream>>>(whh_f, whh_b, wreg, wtail);
    k_embed<<<NNODE, 256, 0, stream>>>(lattice, form, lemma, tag, feats, embB);

    dim3 gE((NNODE+63)/64, G4/64);
    k_gemm_bf16<<<gE, 256, 0, stream>>>(embB, wihfB, XgF, b_f, NNODE, G4, DIN);
    k_gemm_bf16<<<gE, 256, 0, stream>>>(embB, wihbB, XgB, b_b, NNODE, G4, DIN);
    dim3 gD((NNODE+63)/64, DG4/64);
    k_gemm_bf16<<<gD, 256, 0, stream>>>(embB, dwihB, Graw, nullptr, NNODE, DG4, DIN);

    k_lstm_scan<<<2, 512, scan_lds, stream>>>(wreg, wtail, XgF, XgB, enc, h0, c0);

    k_dec_const<<<8, 256, 0, stream>>>(dwhh, db, h0, Kd);
    k_hall<<<NNODE, 512, 0, stream>>>(Graw, Kd, c0, Hall);
    k_scores<<<256, 256, 0, stream>>>(enc, Hall, Sbuf);
    k_decode<<<1, 256, 0, stream>>>(Sbuf, out);
}